// Round 1
// baseline (578.526 us; speedup 1.0000x reference)
//
#include <hip/hip_runtime.h>
#include <hip/hip_bf16.h>

// Problem dims
#define SEQ   2048
#define BATCH 16
#define DIN   512
#define HID   512
#define MROWS (SEQ*BATCH)   // 32768 GEMM rows (s,b)
#define NCOLS (6*HID)       // 3072 GEMM cols (dir,gate,h)
#define KDIM  DIN           // 512

// Scan chunking
#define NC   32             // chunks along S
#define CL   64             // chunk length (NC*CL == SEQ)
#define NSEQ (2*BATCH*HID)  // 16384 independent recurrences

typedef unsigned short u16;
typedef __bf16 bf16x8 __attribute__((ext_vector_type(8)));
typedef float  f32x4  __attribute__((ext_vector_type(4)));

__device__ __forceinline__ u16 f2bf(float x) {
  unsigned u = __float_as_uint(x);
  unsigned r = (u + 0x7fffu + ((u >> 16) & 1u)) >> 16;   // RNE
  return (u16)r;
}

__device__ __forceinline__ void async_ld16(const void* g, void* l) {
  __builtin_amdgcn_global_load_lds(
      (const __attribute__((address_space(1))) void*)g,
      (__attribute__((address_space(3))) void*)l, 16, 0, 0);
}

__device__ __forceinline__ float sig_fast(float x) {
  return __builtin_amdgcn_rcpf(1.f + __expf(-x));
}
__device__ __forceinline__ float tanh_fast(float x) {
  return 1.f - 2.f * __builtin_amdgcn_rcpf(1.f + __expf(2.f * x));
}

// ---- fp32 -> bf16 conversion (vectorized, 4 elems/thread) ----
__global__ void cvt_kernel(const float* __restrict__ in, u16* __restrict__ out, int n4) {
  int i = blockIdx.x * blockDim.x + threadIdx.x;
  if (i >= n4) return;
  const float4 v = ((const float4*)in)[i];
  uint2 r;
  r.x = (unsigned)f2bf(v.x) | ((unsigned)f2bf(v.y) << 16);
  r.y = (unsigned)f2bf(v.z) | ((unsigned)f2bf(v.w) << 16);
  ((uint2*)out)[i] = r;
}

// ---- GEMM + bias + activation epilogue ----
// A: [MROWS][KDIM] bf16 (X), B: [NCOLS][KDIM] bf16 (W_fw rows 0..1535, W_bw rows 1536..3071)
// G layout: [dir*3+gate][m=(s*BATCH+b)][h]  fp32, activated (z->tanh, f/o->sigmoid)
__launch_bounds__(256)
__global__ void gemm_gates(const u16* __restrict__ A, const u16* __restrict__ B,
                           const float* __restrict__ bfw, const float* __restrict__ bbw,
                           float* __restrict__ G)
{
  __shared__ u16 sA[128 * 32];   // 8 KB, row-major [m][k], no pad (global_load_lds)
  __shared__ u16 sB[128 * 32];

  const int t    = threadIdx.x;
  const int wave = t >> 6;
  const int lane = t & 63;
  const int m0 = blockIdx.y * 128;
  const int n0 = blockIdx.x * 128;
  const int wm = (wave >> 1) * 64;   // wave's 64x64 sub-tile
  const int wn = (wave & 1) * 64;

  f32x4 acc[4][4] = {};

  // staging: thread t loads row t/4 (and +64), k-chunk (t%4)*8  -> LDS offset t*8 ushorts
  const int srow = t >> 2;
  const int skcol = (t & 3) * 8;
  const u16* gA = A + (size_t)(m0 + srow) * KDIM + skcol;
  const u16* gB = B + (size_t)(n0 + srow) * KDIM + skcol;
  u16* lA0 = sA + wave * 512;          // wave-uniform bases (lane writes +lane*16B)
  u16* lA1 = sA + 2048 + wave * 512;
  u16* lB0 = sB + wave * 512;
  u16* lB1 = sB + 2048 + wave * 512;

  const int lm = lane & 15;            // fragment row (m or n)
  const int lk = (lane >> 4) * 8;      // fragment k-offset

  for (int kt = 0; kt < KDIM; kt += 32) {
    __syncthreads();                   // all waves done reading previous tile
    async_ld16(gA + kt, lA0);
    async_ld16(gA + kt + (size_t)64 * KDIM, lA1);
    async_ld16(gB + kt, lB0);
    async_ld16(gB + kt + (size_t)64 * KDIM, lB1);
    __syncthreads();                   // compiler drains vmcnt(0) before barrier

    bf16x8 af[4], bfr[4];
#pragma unroll
    for (int mi = 0; mi < 4; mi++)
      af[mi] = *(const bf16x8*)(sA + (wm + mi * 16 + lm) * 32 + lk);
#pragma unroll
    for (int ni = 0; ni < 4; ni++)
      bfr[ni] = *(const bf16x8*)(sB + (wn + ni * 16 + lm) * 32 + lk);
#pragma unroll
    for (int mi = 0; mi < 4; mi++)
#pragma unroll
      for (int ni = 0; ni < 4; ni++)
        acc[mi][ni] = __builtin_amdgcn_mfma_f32_16x16x32_bf16(af[mi], bfr[ni], acc[mi][ni], 0, 0, 0);
  }

  // Epilogue: C/D layout col=lane&15, row=(lane>>4)*4+reg  [m89/m91]
  const int lr4 = (lane >> 4) * 4;
#pragma unroll
  for (int ni = 0; ni < 4; ni++) {
    const int col = n0 + wn + ni * 16 + lm;       // 0..3071
    const int dir = col >= 1536 ? 1 : 0;
    const int rem = col - dir * 1536;             // 0..1535
    const int gate = rem >> 9;                    // 0=z 1=f 2=o
    const int h = rem & 511;
    const float bias = (dir ? bbw : bfw)[rem];
    float* Gp = G + (size_t)(dir * 3 + gate) * MROWS * HID + h;
#pragma unroll
    for (int mi = 0; mi < 4; mi++) {
      const int rbase = m0 + wm + mi * 16 + lr4;
#pragma unroll
      for (int i = 0; i < 4; i++) {
        float v = acc[mi][ni][i] + bias;
        v = (gate == 0) ? tanh_fast(v) : sig_fast(v);
        Gp[(size_t)(rbase + i) * HID] = v;
      }
    }
  }
}

// ---- Scan pass 1: per-chunk composed transform (A,C): h_out = A*h_in + C ----
__global__ void scan_stage1(const float* __restrict__ G, float* __restrict__ AC) {
  const int tid = blockIdx.x * 256 + threadIdx.x;
  const int h     = tid & 511;
  const int chunk = (tid >> 9) & 31;
  const int b     = (tid >> 14) & 15;
  const int dir   = tid >> 18;
  const float* Zp = G + (size_t)(dir * 3 + 0) * MROWS * HID;
  const float* Fp = G + (size_t)(dir * 3 + 1) * MROWS * HID;
  float Aa = 1.f, Cc = 0.f;
  const int tbase = chunk * CL;
  for (int i = 0; i < CL; i++) {
    const int ts = tbase + i;
    const int s = dir ? (SEQ - 1 - ts) : ts;
    const size_t off = ((size_t)s * BATCH + b) * HID + h;
    const float z = Zp[off], f = Fp[off];
    const float a = 1.f - f;
    Cc = a * Cc + f * z;
    Aa = a * Aa;
  }
  const int sidx = (dir * BATCH + b) * HID + h;
  AC[(size_t)chunk * (2 * NSEQ) + sidx] = Aa;
  AC[(size_t)chunk * (2 * NSEQ) + NSEQ + sidx] = Cc;
}

// ---- Scan pass 2: sequential combine over chunks -> carry-in per chunk ----
__global__ void scan_stage2(const float* __restrict__ AC, float* __restrict__ Hin) {
  const int sidx = blockIdx.x * 256 + threadIdx.x;   // 16384 threads
  float carry = 0.f;
  for (int chunk = 0; chunk < NC; chunk++) {
    Hin[(size_t)chunk * NSEQ + sidx] = carry;
    const float Aa = AC[(size_t)chunk * (2 * NSEQ) + sidx];
    const float Cc = AC[(size_t)chunk * (2 * NSEQ) + NSEQ + sidx];
    carry = Aa * carry + Cc;
  }
}

// ---- Scan pass 3: re-scan chunk with true carry-in, apply o, write output ----
__global__ void scan_stage3(const float* __restrict__ G, const float* __restrict__ Hin,
                            float* __restrict__ out) {
  const int tid = blockIdx.x * 256 + threadIdx.x;
  const int h     = tid & 511;
  const int chunk = (tid >> 9) & 31;
  const int b     = (tid >> 14) & 15;
  const int dir   = tid >> 18;
  const float* Zp = G + (size_t)(dir * 3 + 0) * MROWS * HID;
  const float* Fp = G + (size_t)(dir * 3 + 1) * MROWS * HID;
  const float* Op = G + (size_t)(dir * 3 + 2) * MROWS * HID;
  const int sidx = (dir * BATCH + b) * HID + h;
  float hv = Hin[(size_t)chunk * NSEQ + sidx];
  const int tbase = chunk * CL;
  for (int i = 0; i < CL; i++) {
    const int ts = tbase + i;
    const int s = dir ? (SEQ - 1 - ts) : ts;
    const size_t off = ((size_t)s * BATCH + b) * HID + h;
    const float z = Zp[off], f = Fp[off], o = Op[off];
    hv = fmaf(f, z - hv, hv);            // h = (1-f)h + f z
    out[((size_t)s * BATCH + b) * (2 * HID) + (size_t)dir * HID + h] = o * hv;
  }
}

extern "C" void kernel_launch(void* const* d_in, const int* in_sizes, int n_in,
                              void* d_out, int out_size, void* d_ws, size_t ws_size,
                              hipStream_t stream) {
  const float* X   = (const float*)d_in[0];
  const float* Wfw = (const float*)d_in[1];
  const float* bfw = (const float*)d_in[2];
  const float* Wbw = (const float*)d_in[3];
  const float* bbw = (const float*)d_in[4];
  float* out = (float*)d_out;

  char* ws = (char*)d_ws;
  u16*   Xb  = (u16*)ws;                                             // 32 MiB
  u16*   Wb  = (u16*)(ws + (size_t)MROWS * KDIM * 2);                // 3 MiB
  float* G   = (float*)(ws + (size_t)MROWS * KDIM * 2 + (size_t)NCOLS * KDIM * 2); // 384 MiB
  float* AC  = (float*)((char*)G + (size_t)6 * MROWS * HID * 4);     // 4 MiB
  float* Hin = (float*)((char*)AC + (size_t)NC * 2 * NSEQ * 4);      // 2 MiB

  // bf16 conversions
  cvt_kernel<<<(MROWS * KDIM / 4) / 256, 256, 0, stream>>>(X, Xb, MROWS * KDIM / 4);
  cvt_kernel<<<(3 * HID * KDIM / 4) / 256, 256, 0, stream>>>(Wfw, Wb, 3 * HID * KDIM / 4);
  cvt_kernel<<<(3 * HID * KDIM / 4) / 256, 256, 0, stream>>>(Wbw, Wb + (size_t)3 * HID * KDIM,
                                                             3 * HID * KDIM / 4);

  // gates GEMM: grid 24 x 256 tiles of 128x128
  dim3 gg(NCOLS / 128, MROWS / 128);
  gemm_gates<<<gg, 256, 0, stream>>>(Xb, Wb, bfw, bbw, G);

  // chunked linear recurrence
  scan_stage1<<<(NSEQ * NC) / 256, 256, 0, stream>>>(G, AC);
  scan_stage2<<<NSEQ / 256, 256, 0, stream>>>(AC, Hin);
  scan_stage3<<<(NSEQ * NC) / 256, 256, 0, stream>>>(G, Hin, out);
}

// Round 2
// 440.396 us; speedup vs baseline: 1.3137x; 1.3137x over previous
//
#include <hip/hip_runtime.h>
#include <hip/hip_bf16.h>

// Problem dims
#define SEQ   2048
#define BATCH 16
#define DIN   512
#define HID   512
#define MROWS (SEQ*BATCH)   // 32768 GEMM rows (s,b)
#define NCOLS (6*HID)       // 3072 GEMM cols (dir,gate,h)
#define KDIM  DIN           // 512

// Scan chunking
#define NC   32             // chunks along S
#define CL   64             // chunk length (NC*CL == SEQ)
#define NSEQ (2*BATCH*HID)  // 16384 independent recurrences

typedef unsigned short u16;
typedef __bf16 bf16x8 __attribute__((ext_vector_type(8)));
typedef float  f32x4  __attribute__((ext_vector_type(4)));

__device__ __forceinline__ u16 f2bf(float x) {
  unsigned u = __float_as_uint(x);
  unsigned r = (u + 0x7fffu + ((u >> 16) & 1u)) >> 16;   // RNE
  return (u16)r;
}
__device__ __forceinline__ float bflo(unsigned u) { return __uint_as_float(u << 16); }
__device__ __forceinline__ float bfhi(unsigned u) { return __uint_as_float(u & 0xffff0000u); }

__device__ __forceinline__ void async_ld16(const void* g, void* l) {
  __builtin_amdgcn_global_load_lds(
      (const __attribute__((address_space(1))) void*)g,
      (__attribute__((address_space(3))) void*)l, 16, 0, 0);
}

__device__ __forceinline__ float sig_fast(float x) {
  return __builtin_amdgcn_rcpf(1.f + __expf(-x));
}
__device__ __forceinline__ float tanh_fast(float x) {
  return 1.f - 2.f * __builtin_amdgcn_rcpf(1.f + __expf(2.f * x));
}

// ---- fp32 -> bf16 conversion (vectorized, 4 elems/thread) ----
__global__ void cvt_kernel(const float* __restrict__ in, u16* __restrict__ out, int n4) {
  int i = blockIdx.x * blockDim.x + threadIdx.x;
  if (i >= n4) return;
  const float4 v = ((const float4*)in)[i];
  uint2 r;
  r.x = (unsigned)f2bf(v.x) | ((unsigned)f2bf(v.y) << 16);
  r.y = (unsigned)f2bf(v.z) | ((unsigned)f2bf(v.w) << 16);
  ((uint2*)out)[i] = r;
}

// ---- GEMM + bias + activation epilogue (bf16 G output) ----
// A: [MROWS][KDIM] bf16 (X), B: [NCOLS][KDIM] bf16 (W_fw rows 0..1535, W_bw 1536..3071)
// G: 6 slabs [dir*3+gate][m][h] bf16, activated.
// MFMA operands SWAPPED vs naive: D-rows = n(h), D-cols = m -> each lane holds
// 4 consecutive h for a fixed m -> 8B packed bf16 stores.
__launch_bounds__(256)
__global__ void gemm_gates(const u16* __restrict__ A, const u16* __restrict__ B,
                           const float* __restrict__ bfw, const float* __restrict__ bbw,
                           u16* __restrict__ G)
{
  __shared__ u16 sA[128 * 32];   // 8 KB, [row][chunk^swz(row)] (XOR-swizzled k-chunks)
  __shared__ u16 sB[128 * 32];

  const int t    = threadIdx.x;
  const int wave = t >> 6;
  const int lane = t & 63;
  const int m0 = blockIdx.y * 128;
  const int n0 = blockIdx.x * 128;
  const int wm = (wave >> 1) * 64;   // wave's 64x64 sub-tile
  const int wn = (wave & 1) * 64;

  f32x4 acc[4][4] = {};

  // staging: thread t fills LDS row r=t>>2, lds-chunk c=t&3 (16B each).
  // XOR swizzle: lds position (r,c) holds GLOBAL k-chunk c ^ ((r>>1)&3).
  const int srow = t >> 2;
  const int skcol = ((t & 3) ^ ((t >> 3) & 3)) * 8;   // swizzled global k-chunk
  const u16* gA = A + (size_t)(m0 + srow) * KDIM + skcol;
  const u16* gB = B + (size_t)(n0 + srow) * KDIM + skcol;
  u16* lA0 = sA + wave * 512;          // wave-uniform bases (lane writes +lane*16B)
  u16* lA1 = sA + 2048 + wave * 512;
  u16* lB0 = sB + wave * 512;
  u16* lB1 = sB + 2048 + wave * 512;

  const int lm  = lane & 15;            // fragment index (m or n)
  const int q   = lane >> 4;            // k-quad
  const int swz = (lm >> 1) & 3;        // matches staging swizzle: (row>>1)&3
  const int koff = ((q ^ swz) * 8);

  for (int kt = 0; kt < KDIM; kt += 32) {
    __syncthreads();
    async_ld16(gA + kt, lA0);
    async_ld16(gA + kt + (size_t)64 * KDIM, lA1);
    async_ld16(gB + kt, lB0);
    async_ld16(gB + kt + (size_t)64 * KDIM, lB1);
    __syncthreads();

    bf16x8 af[4], bfr[4];
#pragma unroll
    for (int mi = 0; mi < 4; mi++)
      af[mi] = *(const bf16x8*)(sA + (wm + mi * 16 + lm) * 32 + koff);
#pragma unroll
    for (int ni = 0; ni < 4; ni++)
      bfr[ni] = *(const bf16x8*)(sB + (wn + ni * 16 + lm) * 32 + koff);
#pragma unroll
    for (int mi = 0; mi < 4; mi++)
#pragma unroll
      for (int ni = 0; ni < 4; ni++)  // operands swapped: rows=n, cols=m
        acc[mi][ni] = __builtin_amdgcn_mfma_f32_16x16x32_bf16(bfr[ni], af[mi], acc[mi][ni], 0, 0, 0);
  }

  // Epilogue: D layout col=lane&15 (m-index), row=(lane>>4)*4+i (n-index)
  const int q4 = q * 4;
#pragma unroll
  for (int ni = 0; ni < 4; ni++) {
    const int colb = n0 + wn + ni * 16 + q4;      // n base, 4-aligned, wave-uniform gate/dir
    const int dir  = colb >= 1536 ? 1 : 0;
    const int rem  = colb - dir * 1536;           // 0..1535
    const int gate = rem >> 9;                    // 0=z 1=f 2=o
    const int hb   = rem & 511;                   // h base, 4-aligned
    const float4 bias4 = *(const float4*)((dir ? bbw : bfw) + rem);
    u16* Gs = G + (size_t)(dir * 3 + gate) * MROWS * HID + hb;
#pragma unroll
    for (int mi = 0; mi < 4; mi++) {
      const int m = m0 + wm + mi * 16 + lm;
      float v0 = acc[mi][ni][0] + bias4.x;
      float v1 = acc[mi][ni][1] + bias4.y;
      float v2 = acc[mi][ni][2] + bias4.z;
      float v3 = acc[mi][ni][3] + bias4.w;
      if (gate == 0) {
        v0 = tanh_fast(v0); v1 = tanh_fast(v1); v2 = tanh_fast(v2); v3 = tanh_fast(v3);
      } else {
        v0 = sig_fast(v0); v1 = sig_fast(v1); v2 = sig_fast(v2); v3 = sig_fast(v3);
      }
      uint2 pk;
      pk.x = (unsigned)f2bf(v0) | ((unsigned)f2bf(v1) << 16);
      pk.y = (unsigned)f2bf(v2) | ((unsigned)f2bf(v3) << 16);
      *(uint2*)(Gs + (size_t)m * HID) = pk;
    }
  }
}

// ---- Scan pass 1: per-chunk composed transform (A,C), 4 h per thread ----
__global__ void scan_stage1(const u16* __restrict__ G, float* __restrict__ AC) {
  const int tid = blockIdx.x * 256 + threadIdx.x;
  const int h     = (tid & 127) * 4;
  const int chunk = (tid >> 7) & 31;
  const int b     = (tid >> 12) & 15;
  const int dir   = tid >> 16;
  const u16* Zp = G + (size_t)(dir * 3 + 0) * MROWS * HID;
  const u16* Fp = G + (size_t)(dir * 3 + 1) * MROWS * HID;
  float A0 = 1.f, A1 = 1.f, A2 = 1.f, A3 = 1.f;
  float C0 = 0.f, C1 = 0.f, C2 = 0.f, C3 = 0.f;
  const int tbase = chunk * CL;
  for (int i = 0; i < CL; i++) {
    const int ts = tbase + i;
    const int s = dir ? (SEQ - 1 - ts) : ts;
    const size_t off = ((size_t)s * BATCH + b) * HID + h;
    const uint2 zu = *(const uint2*)(Zp + off);
    const uint2 fu = *(const uint2*)(Fp + off);
    const float z0 = bflo(zu.x), z1 = bfhi(zu.x), z2 = bflo(zu.y), z3 = bfhi(zu.y);
    const float f0 = bflo(fu.x), f1 = bfhi(fu.x), f2 = bflo(fu.y), f3 = bfhi(fu.y);
    const float a0 = 1.f - f0, a1 = 1.f - f1, a2 = 1.f - f2, a3 = 1.f - f3;
    C0 = fmaf(a0, C0, f0 * z0); A0 *= a0;
    C1 = fmaf(a1, C1, f1 * z1); A1 *= a1;
    C2 = fmaf(a2, C2, f2 * z2); A2 *= a2;
    C3 = fmaf(a3, C3, f3 * z3); A3 *= a3;
  }
  const int sidx = (dir * BATCH + b) * HID + h;
  *(float4*)&AC[(size_t)chunk * (2 * NSEQ) + sidx]        = make_float4(A0, A1, A2, A3);
  *(float4*)&AC[(size_t)chunk * (2 * NSEQ) + NSEQ + sidx] = make_float4(C0, C1, C2, C3);
}

// ---- Scan pass 2: sequential combine over chunks -> carry-in per chunk ----
__global__ void scan_stage2(const float* __restrict__ AC, float* __restrict__ Hin) {
  const int sidx = blockIdx.x * 256 + threadIdx.x;   // 16384 threads
  float carry = 0.f;
  for (int chunk = 0; chunk < NC; chunk++) {
    Hin[(size_t)chunk * NSEQ + sidx] = carry;
    const float Aa = AC[(size_t)chunk * (2 * NSEQ) + sidx];
    const float Cc = AC[(size_t)chunk * (2 * NSEQ) + NSEQ + sidx];
    carry = fmaf(Aa, carry, Cc);
  }
}

// ---- Scan pass 3: re-scan chunk with carry-in, apply o, write output ----
__global__ void scan_stage3(const u16* __restrict__ G, const float* __restrict__ Hin,
                            float* __restrict__ out) {
  const int tid = blockIdx.x * 256 + threadIdx.x;
  const int h     = (tid & 127) * 4;
  const int chunk = (tid >> 7) & 31;
  const int b     = (tid >> 12) & 15;
  const int dir   = tid >> 16;
  const u16* Zp = G + (size_t)(dir * 3 + 0) * MROWS * HID;
  const u16* Fp = G + (size_t)(dir * 3 + 1) * MROWS * HID;
  const u16* Op = G + (size_t)(dir * 3 + 2) * MROWS * HID;
  const int sidx = (dir * BATCH + b) * HID + h;
  float4 hv = *(const float4*)&Hin[(size_t)chunk * NSEQ + sidx];
  const int tbase = chunk * CL;
  for (int i = 0; i < CL; i++) {
    const int ts = tbase + i;
    const int s = dir ? (SEQ - 1 - ts) : ts;
    const size_t off = ((size_t)s * BATCH + b) * HID + h;
    const uint2 zu = *(const uint2*)(Zp + off);
    const uint2 fu = *(const uint2*)(Fp + off);
    const uint2 ou = *(const uint2*)(Op + off);
    const float z0 = bflo(zu.x), z1 = bfhi(zu.x), z2 = bflo(zu.y), z3 = bfhi(zu.y);
    const float f0 = bflo(fu.x), f1 = bfhi(fu.x), f2 = bflo(fu.y), f3 = bfhi(fu.y);
    hv.x = fmaf(f0, z0 - hv.x, hv.x);
    hv.y = fmaf(f1, z1 - hv.y, hv.y);
    hv.z = fmaf(f2, z2 - hv.z, hv.z);
    hv.w = fmaf(f3, z3 - hv.w, hv.w);
    float4 ov;
    ov.x = bflo(ou.x) * hv.x;
    ov.y = bfhi(ou.x) * hv.y;
    ov.z = bflo(ou.y) * hv.z;
    ov.w = bfhi(ou.y) * hv.w;
    *(float4*)&out[((size_t)s * BATCH + b) * (2 * HID) + (size_t)dir * HID + h] = ov;
  }
}

extern "C" void kernel_launch(void* const* d_in, const int* in_sizes, int n_in,
                              void* d_out, int out_size, void* d_ws, size_t ws_size,
                              hipStream_t stream) {
  const float* X   = (const float*)d_in[0];
  const float* Wfw = (const float*)d_in[1];
  const float* bfw = (const float*)d_in[2];
  const float* Wbw = (const float*)d_in[3];
  const float* bbw = (const float*)d_in[4];
  float* out = (float*)d_out;

  char* ws = (char*)d_ws;
  u16*   Xb  = (u16*)ws;                                             // 32 MiB
  u16*   Wb  = (u16*)(ws + (size_t)MROWS * KDIM * 2);                // 3 MiB
  u16*   G   = (u16*)(ws + (size_t)MROWS * KDIM * 2 + (size_t)NCOLS * KDIM * 2); // 192 MiB
  float* AC  = (float*)((char*)G + (size_t)6 * MROWS * HID * 2);     // 4 MiB
  float* Hin = (float*)((char*)AC + (size_t)NC * 2 * NSEQ * 4);      // 2 MiB

  // bf16 conversions
  cvt_kernel<<<(MROWS * KDIM / 4) / 256, 256, 0, stream>>>(X, Xb, MROWS * KDIM / 4);
  cvt_kernel<<<(3 * HID * KDIM / 4) / 256, 256, 0, stream>>>(Wfw, Wb, 3 * HID * KDIM / 4);
  cvt_kernel<<<(3 * HID * KDIM / 4) / 256, 256, 0, stream>>>(Wbw, Wb + (size_t)3 * HID * KDIM,
                                                             3 * HID * KDIM / 4);

  // gates GEMM: grid 24 x 256 tiles of 128x128
  dim3 gg(NCOLS / 128, MROWS / 128);
  gemm_gates<<<gg, 256, 0, stream>>>(Xb, Wb, bfw, bbw, G);

  // chunked linear recurrence (4 h per thread)
  scan_stage1<<<(NSEQ * NC / 4) / 256, 256, 0, stream>>>(G, AC);
  scan_stage2<<<NSEQ / 256, 256, 0, stream>>>(AC, Hin);
  scan_stage3<<<(NSEQ * NC / 4) / 256, 256, 0, stream>>>(G, Hin, out);
}

// Round 3
// 408.502 us; speedup vs baseline: 1.4162x; 1.0781x over previous
//
#include <hip/hip_runtime.h>
#include <hip/hip_bf16.h>

// Problem dims
#define SEQ   2048
#define BATCH 16
#define DIN   512
#define HID   512
#define MROWS (SEQ*BATCH)   // 32768 GEMM rows (s,b)
#define NCOLS (6*HID)       // 3072 GEMM cols (dir,gate,h)
#define KDIM  DIN           // 512

// Scan chunking
#define NC   64             // chunks along S
#define CL   32             // chunk length (NC*CL == SEQ)
#define NSEQ (2*BATCH*HID)  // 16384 independent recurrences

typedef unsigned short u16;
typedef __bf16 bf16x8 __attribute__((ext_vector_type(8)));
typedef float  f32x4  __attribute__((ext_vector_type(4)));

__device__ __forceinline__ u16 f2bf(float x) {
  unsigned u = __float_as_uint(x);
  unsigned r = (u + 0x7fffu + ((u >> 16) & 1u)) >> 16;   // RNE
  return (u16)r;
}
__device__ __forceinline__ float bflo(unsigned u) { return __uint_as_float(u << 16); }
__device__ __forceinline__ float bfhi(unsigned u) { return __uint_as_float(u & 0xffff0000u); }

__device__ __forceinline__ void async_ld16(const void* g, void* l) {
  __builtin_amdgcn_global_load_lds(
      (const __attribute__((address_space(1))) void*)g,
      (__attribute__((address_space(3))) void*)l, 16, 0, 0);
}

__device__ __forceinline__ float sig_fast(float x) {
  return __builtin_amdgcn_rcpf(1.f + __expf(-x));
}
__device__ __forceinline__ float tanh_fast(float x) {
  return 1.f - 2.f * __builtin_amdgcn_rcpf(1.f + __expf(2.f * x));
}

// ---- fp32 -> bf16 conversion (vectorized, 4 elems/thread) ----
__global__ void cvt_kernel(const float* __restrict__ in, u16* __restrict__ out, int n4) {
  int i = blockIdx.x * blockDim.x + threadIdx.x;
  if (i >= n4) return;
  const float4 v = ((const float4*)in)[i];
  uint2 r;
  r.x = (unsigned)f2bf(v.x) | ((unsigned)f2bf(v.y) << 16);
  r.y = (unsigned)f2bf(v.z) | ((unsigned)f2bf(v.w) << 16);
  ((uint2*)out)[i] = r;
}

// ---- GEMM + bias + activation epilogue (bf16 G output), BK=64 ----
// A: [MROWS][KDIM] bf16 (X), B: [NCOLS][KDIM] bf16 (W_fw rows 0..1535, W_bw 1536..3071)
// G: 6 slabs [dir*3+gate][m][h] bf16, activated.
// LDS tiles 128x64, row stride 64 u16 (128 B). Slot (r,c) holds global 16B
// k-chunk c ^ (r&7)  -> read phase: 16 lanes hit 8 bank-quads 2-way (free).
__launch_bounds__(256)
__global__ void gemm_gates(const u16* __restrict__ A, const u16* __restrict__ B,
                           const float* __restrict__ bfw, const float* __restrict__ bbw,
                           u16* __restrict__ G)
{
  __shared__ u16 sA[128 * 64];   // 16 KB
  __shared__ u16 sB[128 * 64];   // 16 KB

  const int t    = threadIdx.x;
  const int wave = t >> 6;
  const int lane = t & 63;
  const int m0 = blockIdx.y * 128;
  const int n0 = blockIdx.x * 128;
  const int wm = (wave >> 1) * 64;   // wave's 64x64 sub-tile
  const int wn = (wave & 1) * 64;

  f32x4 acc[4][4] = {};

  // staging: one async_ld16 per wave fills 8 rows x 8 chunks (1024 B contig LDS).
  // lane -> (r_local = lane>>3, c = lane&7); global chunk g = c ^ r_local (rbase%8==0).
  const int rloc = lane >> 3;
  const int gch  = (lane & 7) ^ rloc;
  const u16* gA = A + (size_t)(m0 + wave * 32 + rloc) * KDIM + gch * 8;
  const u16* gB = B + (size_t)(n0 + wave * 32 + rloc) * KDIM + gch * 8;

  const int lm  = lane & 15;            // fragment index (m or n)
  const int q   = lane >> 4;            // k-quad within a 32-k step
  const int xs  = lm & 7;               // read-side swizzle = r&7

  for (int kt = 0; kt < KDIM; kt += 64) {
    __syncthreads();
#pragma unroll
    for (int j = 0; j < 4; j++) {
      async_ld16(gA + kt + (size_t)(j * 8) * KDIM, sA + (wave * 32 + j * 8) * 64);
      async_ld16(gB + kt + (size_t)(j * 8) * KDIM, sB + (wave * 32 + j * 8) * 64);
    }
    __syncthreads();

#pragma unroll
    for (int s = 0; s < 2; s++) {
      const int cofs = ((s * 4 + q) ^ xs) * 8;
      bf16x8 af[4], bfr[4];
#pragma unroll
      for (int mi = 0; mi < 4; mi++)
        af[mi] = *(const bf16x8*)(sA + (wm + mi * 16 + lm) * 64 + cofs);
#pragma unroll
      for (int ni = 0; ni < 4; ni++)
        bfr[ni] = *(const bf16x8*)(sB + (wn + ni * 16 + lm) * 64 + cofs);
#pragma unroll
      for (int mi = 0; mi < 4; mi++)
#pragma unroll
        for (int ni = 0; ni < 4; ni++)  // operands swapped: D rows=n, cols=m
          acc[mi][ni] = __builtin_amdgcn_mfma_f32_16x16x32_bf16(bfr[ni], af[mi], acc[mi][ni], 0, 0, 0);
    }
  }

  // Epilogue: D layout col=lane&15 (m-index), row=(lane>>4)*4+i (n-index)
  const int q4 = q * 4;
#pragma unroll
  for (int ni = 0; ni < 4; ni++) {
    const int colb = n0 + wn + ni * 16 + q4;      // n base, 4-aligned, wave-uniform gate/dir
    const int dir  = colb >= 1536 ? 1 : 0;
    const int rem  = colb - dir * 1536;           // 0..1535
    const int gate = rem >> 9;                    // 0=z 1=f 2=o
    const int hb   = rem & 511;                   // h base, 4-aligned
    const float4 bias4 = *(const float4*)((dir ? bbw : bfw) + rem);
    u16* Gs = G + (size_t)(dir * 3 + gate) * MROWS * HID + hb;
#pragma unroll
    for (int mi = 0; mi < 4; mi++) {
      const int m = m0 + wm + mi * 16 + lm;
      float v0 = acc[mi][ni][0] + bias4.x;
      float v1 = acc[mi][ni][1] + bias4.y;
      float v2 = acc[mi][ni][2] + bias4.z;
      float v3 = acc[mi][ni][3] + bias4.w;
      if (gate == 0) {
        v0 = tanh_fast(v0); v1 = tanh_fast(v1); v2 = tanh_fast(v2); v3 = tanh_fast(v3);
      } else {
        v0 = sig_fast(v0); v1 = sig_fast(v1); v2 = sig_fast(v2); v3 = sig_fast(v3);
      }
      uint2 pk;
      pk.x = (unsigned)f2bf(v0) | ((unsigned)f2bf(v1) << 16);
      pk.y = (unsigned)f2bf(v2) | ((unsigned)f2bf(v3) << 16);
      *(uint2*)(Gs + (size_t)m * HID) = pk;
    }
  }
}

// ---- Scan pass 1: per-chunk composed transform (A,C), 4 h per thread ----
__global__ void scan_stage1(const u16* __restrict__ G, float* __restrict__ AC) {
  const int tid = blockIdx.x * 256 + threadIdx.x;
  const int h     = (tid & 127) * 4;
  const int chunk = (tid >> 7) & 63;
  const int b     = (tid >> 13) & 15;
  const int dir   = tid >> 17;
  const u16* Zp = G + (size_t)(dir * 3 + 0) * MROWS * HID;
  const u16* Fp = G + (size_t)(dir * 3 + 1) * MROWS * HID;
  float A0 = 1.f, A1 = 1.f, A2 = 1.f, A3 = 1.f;
  float C0 = 0.f, C1 = 0.f, C2 = 0.f, C3 = 0.f;
  const int tbase = chunk * CL;
#pragma unroll 8
  for (int i = 0; i < CL; i++) {
    const int ts = tbase + i;
    const int s = dir ? (SEQ - 1 - ts) : ts;
    const size_t off = ((size_t)s * BATCH + b) * HID + h;
    const uint2 zu = *(const uint2*)(Zp + off);
    const uint2 fu = *(const uint2*)(Fp + off);
    const float z0 = bflo(zu.x), z1 = bfhi(zu.x), z2 = bflo(zu.y), z3 = bfhi(zu.y);
    const float f0 = bflo(fu.x), f1 = bfhi(fu.x), f2 = bflo(fu.y), f3 = bfhi(fu.y);
    const float a0 = 1.f - f0, a1 = 1.f - f1, a2 = 1.f - f2, a3 = 1.f - f3;
    C0 = fmaf(a0, C0, f0 * z0); A0 *= a0;
    C1 = fmaf(a1, C1, f1 * z1); A1 *= a1;
    C2 = fmaf(a2, C2, f2 * z2); A2 *= a2;
    C3 = fmaf(a3, C3, f3 * z3); A3 *= a3;
  }
  const int sidx = (dir * BATCH + b) * HID + h;
  *(float4*)&AC[(size_t)chunk * (2 * NSEQ) + sidx]        = make_float4(A0, A1, A2, A3);
  *(float4*)&AC[(size_t)chunk * (2 * NSEQ) + NSEQ + sidx] = make_float4(C0, C1, C2, C3);
}

// ---- Scan pass 2: sequential combine over chunks -> carry-in per chunk ----
__global__ void scan_stage2(const float* __restrict__ AC, float* __restrict__ Hin) {
  const int sidx = blockIdx.x * 256 + threadIdx.x;   // 16384 threads
  float carry = 0.f;
  for (int chunk = 0; chunk < NC; chunk++) {
    Hin[(size_t)chunk * NSEQ + sidx] = carry;
    const float Aa = AC[(size_t)chunk * (2 * NSEQ) + sidx];
    const float Cc = AC[(size_t)chunk * (2 * NSEQ) + NSEQ + sidx];
    carry = fmaf(Aa, carry, Cc);
  }
}

// ---- Scan pass 3: re-scan chunk with carry-in, apply o, write output ----
__global__ void scan_stage3(const u16* __restrict__ G, const float* __restrict__ Hin,
                            float* __restrict__ out) {
  const int tid = blockIdx.x * 256 + threadIdx.x;
  const int h     = (tid & 127) * 4;
  const int chunk = (tid >> 7) & 63;
  const int b     = (tid >> 13) & 15;
  const int dir   = tid >> 17;
  const u16* Zp = G + (size_t)(dir * 3 + 0) * MROWS * HID;
  const u16* Fp = G + (size_t)(dir * 3 + 1) * MROWS * HID;
  const u16* Op = G + (size_t)(dir * 3 + 2) * MROWS * HID;
  const int sidx = (dir * BATCH + b) * HID + h;
  float4 hv = *(const float4*)&Hin[(size_t)chunk * NSEQ + sidx];
  const int tbase = chunk * CL;
#pragma unroll 8
  for (int i = 0; i < CL; i++) {
    const int ts = tbase + i;
    const int s = dir ? (SEQ - 1 - ts) : ts;
    const size_t off = ((size_t)s * BATCH + b) * HID + h;
    const uint2 zu = *(const uint2*)(Zp + off);
    const uint2 fu = *(const uint2*)(Fp + off);
    const uint2 ou = *(const uint2*)(Op + off);
    const float z0 = bflo(zu.x), z1 = bfhi(zu.x), z2 = bflo(zu.y), z3 = bfhi(zu.y);
    const float f0 = bflo(fu.x), f1 = bfhi(fu.x), f2 = bflo(fu.y), f3 = bfhi(fu.y);
    hv.x = fmaf(f0, z0 - hv.x, hv.x);
    hv.y = fmaf(f1, z1 - hv.y, hv.y);
    hv.z = fmaf(f2, z2 - hv.z, hv.z);
    hv.w = fmaf(f3, z3 - hv.w, hv.w);
    f32x4 ov;
    ov[0] = bflo(ou.x) * hv.x;
    ov[1] = bfhi(ou.x) * hv.y;
    ov[2] = bflo(ou.y) * hv.z;
    ov[3] = bfhi(ou.y) * hv.w;
    __builtin_nontemporal_store(ov,
        (f32x4*)&out[((size_t)s * BATCH + b) * (2 * HID) + (size_t)dir * HID + h]);
  }
}

extern "C" void kernel_launch(void* const* d_in, const int* in_sizes, int n_in,
                              void* d_out, int out_size, void* d_ws, size_t ws_size,
                              hipStream_t stream) {
  const float* X   = (const float*)d_in[0];
  const float* Wfw = (const float*)d_in[1];
  const float* bfw = (const float*)d_in[2];
  const float* Wbw = (const float*)d_in[3];
  const float* bbw = (const float*)d_in[4];
  float* out = (float*)d_out;

  char* ws = (char*)d_ws;
  u16*   Xb  = (u16*)ws;                                             // 32 MiB
  u16*   Wb  = (u16*)(ws + (size_t)MROWS * KDIM * 2);                // 3 MiB
  u16*   G   = (u16*)(ws + (size_t)MROWS * KDIM * 2 + (size_t)NCOLS * KDIM * 2); // 192 MiB
  float* AC  = (float*)((char*)G + (size_t)6 * MROWS * HID * 2);     // 8 MiB
  float* Hin = (float*)((char*)AC + (size_t)NC * 2 * NSEQ * 4);      // 4 MiB

  // bf16 conversions
  cvt_kernel<<<(MROWS * KDIM / 4) / 256, 256, 0, stream>>>(X, Xb, MROWS * KDIM / 4);
  cvt_kernel<<<(3 * HID * KDIM / 4) / 256, 256, 0, stream>>>(Wfw, Wb, 3 * HID * KDIM / 4);
  cvt_kernel<<<(3 * HID * KDIM / 4) / 256, 256, 0, stream>>>(Wbw, Wb + (size_t)3 * HID * KDIM,
                                                             3 * HID * KDIM / 4);

  // gates GEMM: grid 24 x 256 tiles of 128x128
  dim3 gg(NCOLS / 128, MROWS / 128);
  gemm_gates<<<gg, 256, 0, stream>>>(Xb, Wb, bfw, bbw, G);

  // chunked linear recurrence (4 h per thread, 64 chunks)
  scan_stage1<<<(NSEQ * NC / 4) / 256, 256, 0, stream>>>(G, AC);
  scan_stage2<<<NSEQ / 256, 256, 0, stream>>>(AC, Hin);
  scan_stage3<<<(NSEQ * NC / 4) / 256, 256, 0, stream>>>(G, Hin, out);
}